// Round 10
// baseline (301.679 us; speedup 1.0000x reference)
//
#include <hip/hip_runtime.h>

namespace {

constexpr int kN = 50000, kE = 200000, kG = 500;
constexpr float kEps = 1e-5f;
constexpr int kNB = (kN + 255) / 256;   // 196 node chunks
constexpr int kEB = (kE + 255) / 256;   // 782 edge chunks
constexpr int kYB = (kN + 63) / 64;     // 782 y_root tiles (64 nodes, 256 thr)

typedef short v8s __attribute__((ext_vector_type(8)));
typedef float v4f __attribute__((ext_vector_type(4)));

struct U3 { unsigned a, b, c; };       // 12B gather payload -> global_load_dwordx3

__device__ __forceinline__ unsigned short bf16rn(float x) {
    unsigned u = __float_as_uint(x);
    return (unsigned short)((u + 0x7FFFu + ((u >> 16) & 1u)) >> 16);
}
__device__ __forceinline__ float bf16lo(unsigned p) { return __uint_as_float(p << 16); }
__device__ __forceinline__ float bf16hi(unsigned p) { return __uint_as_float(p & 0xFFFF0000u); }
__device__ __forceinline__ unsigned pk2(float a, float b) {
    return (unsigned)bf16rn(a) | ((unsigned)bf16rn(b) << 16);
}

// ---- degree histogram by dst + fused bf16 weight prepack. ----
__global__ __launch_bounds__(256) void deg_hist(
    const int* __restrict__ ei, int* __restrict__ deg,
    const float* __restrict__ W2all, const float* __restrict__ b2all,
    const float* __restrict__ rWall, unsigned short* __restrict__ Wb)
{
    int e = blockIdx.x * 256 + threadIdx.x;
    if (e < kE) atomicAdd(&deg[ei[kE + e]], 1);
    if (e < 3 * 8192) {
        int l = e >> 13, i = e & 8191;
        int co = i >> 5, c = i & 31, d = co >> 3, k = co & 7;
        const float* W2 = W2all + (size_t)l * 5120;
        float v = (k < 5) ? W2[k * 1024 + c * 32 + d]
                : (k == 5) ? b2all[(size_t)l * 1024 + c * 32 + d]
                : (k == 6) ? rWall[(size_t)l * 1024 + c * 32 + d] : 0.f;
        Wb[(size_t)l * 8192 + co * 32 + c] = bf16rn(v);
    }
}

// ---- h = leaky(x @ lin_W + lin_b), fp32 [n][c], MFMA (A=nodes). ----
__global__ __launch_bounds__(1024) void init_h(
    const float* __restrict__ x, const float* __restrict__ W,
    const float* __restrict__ b, float* __restrict__ hbuf,
    int* __restrict__ deg, float* __restrict__ stats)
{
    __shared__ unsigned short sx[256 * 96];
    __shared__ unsigned short sW[32 * 96];
    int t = threadIdx.x;
    {
        int z = blockIdx.x * 256 + t;
        if (t < 256 && z < kN) deg[z] = 0;
        if (blockIdx.x == 0) for (int i = t; i < 6144; i += 1024) stats[i] = 0.f;
    }
    for (int i = t; i < 256 * 96; i += 1024) sx[i] = 0;
    for (int i = t; i < 32 * 96; i += 1024) sW[i] = 0;
    __syncthreads();
    int tb = blockIdx.x * 256;
    int cnt = min(256, kN - tb);
    for (int i = t; i < cnt * 75; i += 1024) {
        int n = i / 75, f = i - n * 75;
        sx[n * 96 + f] = bf16rn(x[(size_t)tb * 75 + i]);
    }
    for (int i = t; i < 75 * 32; i += 1024) {
        int f = i >> 5, c = i & 31;
        sW[c * 96 + f] = bf16rn(W[i]);
    }
    __syncthreads();
    int l15 = t & 15, quad = (t >> 4) & 3, w = t >> 6;
    #pragma unroll
    for (int tile = 0; tile < 2; ++tile) {
        v4f acc = {0.f, 0.f, 0.f, 0.f};
        #pragma unroll
        for (int kc = 0; kc < 3; ++kc) {
            v8s a  = *(const v8s*)&sx[(w * 16 + l15) * 96 + kc * 32 + quad * 8];
            v8s bb = *(const v8s*)&sW[(tile * 16 + l15) * 96 + kc * 32 + quad * 8];
            acc = __builtin_amdgcn_mfma_f32_16x16x32_bf16(a, bb, acc, 0, 0, 0);
        }
        int c = tile * 16 + l15;
        float bc = b[c];
        #pragma unroll
        for (int r = 0; r < 4; ++r) {
            int n = tb + w * 16 + quad * 4 + r;
            if (n < kN) {
                float v = acc[r] + bc;
                hbuf[(size_t)n * 32 + c] = v > 0.f ? v : 0.01f * v;
            }
        }
    }
}

// ---- fused scan (replaces scan_part + scan_add): each block sums its
// predecessor chunks directly (<=194 coalesced L2-hot loads/lane), then
// block-local exclusive scan -> cursor. One dispatch fewer. ----
__global__ __launch_bounds__(256) void scan_fused(
    const int* __restrict__ deg, int* __restrict__ cursor)
{
    __shared__ int sc[256];
    int t = threadIdx.x;
    int bid = blockIdx.x;
    int part = 0;
    for (int c = 0; c < bid; ++c) part += deg[c * 256 + t];
    sc[t] = part;
    __syncthreads();
    #pragma unroll
    for (int off = 128; off > 0; off >>= 1) {
        if (t < off) sc[t] += sc[t + off];
        __syncthreads();
    }
    int sOff = sc[0];
    __syncthreads();
    int idx = bid * 256 + t;
    int v = (idx < kN) ? deg[idx] : 0;
    sc[t] = v;
    __syncthreads();
    #pragma unroll
    for (int off = 1; off < 256; off <<= 1) {
        int u = (t >= off) ? sc[t - off] : 0;
        __syncthreads();
        sc[t] += u;
        __syncthreads();
    }
    if (idx < kN) cursor[idx] = sOff + sc[t] - v;
}

// ---- hid = relu(ea@W1+b1), 3 layers, into dst-sorted CSR slots. ----
__global__ __launch_bounds__(256) void hid_pre(
    const float* __restrict__ ea, const float* __restrict__ W1,
    const float* __restrict__ b1, const int* __restrict__ ei,
    int* __restrict__ cursor, uint4* __restrict__ hq)
{
    __shared__ float sE[256 * 13];
    __shared__ float sW[195];
    int t = threadIdx.x;
    for (int i = t; i < 195; i += 256) sW[i] = (i < 180) ? W1[i] : b1[i - 180];
    int base = blockIdx.x * 256;
    int cnt = min(256, kE - base);
    for (int i = t; i < cnt * 12; i += 256) {
        int el = i / 12, f = i - el * 12;
        sE[el * 13 + f] = ea[(size_t)base * 12 + i];
    }
    __syncthreads();
    if (t >= cnt) return;
    int e = base + t;
    unsigned src = (unsigned)ei[e];
    unsigned dst = (unsigned)ei[kE + e];
    int pos = atomicAdd(&cursor[dst], 1);
    float ef[12];
    #pragma unroll
    for (int j = 0; j < 12; ++j) ef[j] = sE[t * 13 + j];
    #pragma unroll
    for (int l = 0; l < 3; ++l) {
        float h[5];
        #pragma unroll
        for (int k = 0; k < 5; ++k) h[k] = sW[180 + l * 5 + k];
        #pragma unroll
        for (int f = 0; f < 12; ++f)
            #pragma unroll
            for (int k = 0; k < 5; ++k)
                h[k] = fmaf(ef[f], sW[l * 60 + f * 5 + k], h[k]);
        #pragma unroll
        for (int k = 0; k < 5; ++k) h[k] = h[k] > 0.f ? h[k] : 0.f;
        hq[(size_t)l * kE + pos] = make_uint4(
            pk2(h[0], h[1]), pk2(h[2], h[3]),
            (unsigned)bf16rn(h[4]) | (src << 16), dst);
    }
}

// ---- y_root v3 (R8 verbatim, 273.0us-verified): ZERO LDS, zero barriers.
// A-fragments direct from prepacked Wb; B-fragment = own node's 8 channels
// in registers (BN consts via shfl). Stores: scattered-dword [n][96]
// (gather-optimal, R7 frozen; LDS output staging refuted R6+R9). ----
__global__ __launch_bounds__(256) void y_root(
    const float* __restrict__ hbuf, float* __restrict__ obuf,
    const unsigned short* __restrict__ Wb, const float* __restrict__ convb,
    const float* __restrict__ statsR,
    const float* __restrict__ gPrev, const float* __restrict__ bPrev,
    int first, unsigned* __restrict__ Ydw)
{
    int t = threadIdx.x;
    int l15 = t & 15, quad = (t >> 4) & 3, w = t >> 6;
    int n = blockIdx.x * 64 + w * 16 + l15;
    int c0 = quad * 8;
    float muO = 0.f, ivgO = 0.f, bbO = 0.f;
    if (!first) {
        int c = t & 31;
        float sum = 0.f, sq = 0.f;
        #pragma unroll
        for (int r = 0; r < 32; ++r) {
            sum += statsR[r * 64 + c];
            sq  += statsR[r * 64 + 32 + c];
        }
        float m = sum * (1.f / kN);
        float var = sq * (1.f / kN) - m * m;
        muO = m; ivgO = rsqrtf(var + kEps) * gPrev[c]; bbO = bPrev[c];
    }
    v8s bn_ = {0, 0, 0, 0, 0, 0, 0, 0};
    if (n < kN) {
        if (first) {
            const float* hp = hbuf + (size_t)n * 32 + c0;
            #pragma unroll
            for (int j = 0; j < 8; ++j)
                bn_[j] = (short)bf16rn(hp[j]);
        } else {
            const float* op = obuf + (size_t)n * 32 + c0;
            #pragma unroll
            for (int j = 0; j < 8; ++j) {
                float m  = __shfl(muO,  c0 + j, 32);
                float iv = __shfl(ivgO, c0 + j, 32);
                float bv = __shfl(bbO,  c0 + j, 32);
                float v = (op[j] - m) * iv + bv;
                v = v > 0.f ? v : 0.01f * v;
                bn_[j] = (short)bf16rn(v);
            }
        }
    }
    #pragma unroll
    for (int i = 0; i < 16; ++i) {
        v8s a = *(const v8s*)&Wb[(i * 16 + l15) * 32 + c0];
        v4f acc = {0.f, 0.f, 0.f, 0.f};
        acc = __builtin_amdgcn_mfma_f32_16x16x32_bf16(a, bn_, acc, 0, 0, 0);
        if (n < kN) {
            int cb = i * 16 + quad * 4;
            int d = cb >> 3, koff = cb & 7;
            if (koff == 0) {
                Ydw[(size_t)n * 96 + d * 3]     = pk2(acc[0], acc[1]); // k0,k1
                Ydw[(size_t)n * 96 + d * 3 + 1] = pk2(acc[2], acc[3]); // k2,k3
            } else {
                Ydw[(size_t)n * 96 + d * 3 + 2] = pk2(acc[0], acc[1]); // k4,k5
                obuf[(size_t)n * 32 + d] = acc[2] + convb[d];          // k6
            }
        }
    }
}

// ---- edge_scat: 8 edges/group, 12B dwordx3 gathers, run-merged atomics. ----
__global__ __launch_bounds__(256) void edge_scat(
    const uint4* __restrict__ hq, const unsigned* __restrict__ Ydw,
    float* __restrict__ obuf)
{
    int gid = blockIdx.x * 256 + threadIdx.x;
    int grp = gid >> 5;                 // exactly kE/8 = 25000 groups
    int d = gid & 31;
    int e0 = grp * 8;
    uint4 q0 = hq[e0],     q1 = hq[e0 + 1], q2 = hq[e0 + 2], q3 = hq[e0 + 3];
    uint4 q4 = hq[e0 + 4], q5 = hq[e0 + 5], q6 = hq[e0 + 6], q7 = hq[e0 + 7];
    U3 P0 = *(const U3*)(Ydw + ((q0.z >> 16) * 96u + d * 3u));
    U3 P1 = *(const U3*)(Ydw + ((q1.z >> 16) * 96u + d * 3u));
    U3 P2 = *(const U3*)(Ydw + ((q2.z >> 16) * 96u + d * 3u));
    U3 P3 = *(const U3*)(Ydw + ((q3.z >> 16) * 96u + d * 3u));
    U3 P4 = *(const U3*)(Ydw + ((q4.z >> 16) * 96u + d * 3u));
    U3 P5 = *(const U3*)(Ydw + ((q5.z >> 16) * 96u + d * 3u));
    U3 P6 = *(const U3*)(Ydw + ((q6.z >> 16) * 96u + d * 3u));
    U3 P7 = *(const U3*)(Ydw + ((q7.z >> 16) * 96u + d * 3u));
    float m0 = bf16hi(P0.c);
    m0 = fmaf(bf16lo(q0.x), bf16lo(P0.a), m0);
    m0 = fmaf(bf16hi(q0.x), bf16hi(P0.a), m0);
    m0 = fmaf(bf16lo(q0.y), bf16lo(P0.b), m0);
    m0 = fmaf(bf16hi(q0.y), bf16hi(P0.b), m0);
    m0 = fmaf(bf16lo(q0.z), bf16lo(P0.c), m0);
    float m1 = bf16hi(P1.c);
    m1 = fmaf(bf16lo(q1.x), bf16lo(P1.a), m1);
    m1 = fmaf(bf16hi(q1.x), bf16hi(P1.a), m1);
    m1 = fmaf(bf16lo(q1.y), bf16lo(P1.b), m1);
    m1 = fmaf(bf16hi(q1.y), bf16hi(P1.b), m1);
    m1 = fmaf(bf16lo(q1.z), bf16lo(P1.c), m1);
    float m2 = bf16hi(P2.c);
    m2 = fmaf(bf16lo(q2.x), bf16lo(P2.a), m2);
    m2 = fmaf(bf16hi(q2.x), bf16hi(P2.a), m2);
    m2 = fmaf(bf16lo(q2.y), bf16lo(P2.b), m2);
    m2 = fmaf(bf16hi(q2.y), bf16hi(P2.b), m2);
    m2 = fmaf(bf16lo(q2.z), bf16lo(P2.c), m2);
    float m3 = bf16hi(P3.c);
    m3 = fmaf(bf16lo(q3.x), bf16lo(P3.a), m3);
    m3 = fmaf(bf16hi(q3.x), bf16hi(P3.a), m3);
    m3 = fmaf(bf16lo(q3.y), bf16lo(P3.b), m3);
    m3 = fmaf(bf16hi(q3.y), bf16hi(P3.b), m3);
    m3 = fmaf(bf16lo(q3.z), bf16lo(P3.c), m3);
    float m4 = bf16hi(P4.c);
    m4 = fmaf(bf16lo(q4.x), bf16lo(P4.a), m4);
    m4 = fmaf(bf16hi(q4.x), bf16hi(P4.a), m4);
    m4 = fmaf(bf16lo(q4.y), bf16lo(P4.b), m4);
    m4 = fmaf(bf16hi(q4.y), bf16hi(P4.b), m4);
    m4 = fmaf(bf16lo(q4.z), bf16lo(P4.c), m4);
    float m5 = bf16hi(P5.c);
    m5 = fmaf(bf16lo(q5.x), bf16lo(P5.a), m5);
    m5 = fmaf(bf16hi(q5.x), bf16hi(P5.a), m5);
    m5 = fmaf(bf16lo(q5.y), bf16lo(P5.b), m5);
    m5 = fmaf(bf16hi(q5.y), bf16hi(P5.b), m5);
    m5 = fmaf(bf16lo(q5.z), bf16lo(P5.c), m5);
    float m6 = bf16hi(P6.c);
    m6 = fmaf(bf16lo(q6.x), bf16lo(P6.a), m6);
    m6 = fmaf(bf16hi(q6.x), bf16hi(P6.a), m6);
    m6 = fmaf(bf16lo(q6.y), bf16lo(P6.b), m6);
    m6 = fmaf(bf16hi(q6.y), bf16hi(P6.b), m6);
    m6 = fmaf(bf16lo(q6.z), bf16lo(P6.c), m6);
    float m7 = bf16hi(P7.c);
    m7 = fmaf(bf16lo(q7.x), bf16lo(P7.a), m7);
    m7 = fmaf(bf16hi(q7.x), bf16hi(P7.a), m7);
    m7 = fmaf(bf16lo(q7.y), bf16lo(P7.b), m7);
    m7 = fmaf(bf16hi(q7.y), bf16hi(P7.b), m7);
    m7 = fmaf(bf16lo(q7.z), bf16lo(P7.c), m7);
    float acc = m0;
    unsigned cur = q0.w;
    if (q1.w == cur) acc += m1;
    else { atomicAdd(&obuf[cur * 32u + d], acc); cur = q1.w; acc = m1; }
    if (q2.w == cur) acc += m2;
    else { atomicAdd(&obuf[cur * 32u + d], acc); cur = q2.w; acc = m2; }
    if (q3.w == cur) acc += m3;
    else { atomicAdd(&obuf[cur * 32u + d], acc); cur = q3.w; acc = m3; }
    if (q4.w == cur) acc += m4;
    else { atomicAdd(&obuf[cur * 32u + d], acc); cur = q4.w; acc = m4; }
    if (q5.w == cur) acc += m5;
    else { atomicAdd(&obuf[cur * 32u + d], acc); cur = q5.w; acc = m5; }
    if (q6.w == cur) acc += m6;
    else { atomicAdd(&obuf[cur * 32u + d], acc); cur = q6.w; acc = m6; }
    if (q7.w == cur) acc += m7;
    else { atomicAdd(&obuf[cur * 32u + d], acc); cur = q7.w; acc = m7; }
    atomicAdd(&obuf[cur * 32u + d], acc);
}

// ---- BN stats into 32 replica buffers (16-way -> 16x less per-address
// atomic serialization vs 8 replicas); last layer also inits out=pred_b. ----
__global__ __launch_bounds__(256) void bn_reduce(
    const float* __restrict__ obuf, float* __restrict__ statsR,
    float* __restrict__ out, const float* __restrict__ pred_b, int last)
{
    __shared__ float ls[256];
    __shared__ float lq[256];
    int t = threadIdx.x;
    {
        int gi = blockIdx.x * 256 + t;
        if (last && gi < kG) out[gi] = pred_b[0];
    }
    int c = t & 31, row = t >> 5;
    float s = 0.f, q = 0.f;
    for (int n = blockIdx.x * 8 + row; n < kN; n += gridDim.x * 8) {
        float v = obuf[(size_t)n * 32 + c];
        s += v; q += v * v;
    }
    ls[t] = s; lq[t] = q;
    __syncthreads();
    if (t < 128) { ls[t] += ls[t + 128]; lq[t] += lq[t + 128]; }
    __syncthreads();
    if (t < 64) { ls[t] += ls[t + 64]; lq[t] += lq[t + 64]; }
    __syncthreads();
    if (t < 32) {
        float* rep = statsR + (blockIdx.x & 31) * 64;
        atomicAdd(&rep[t], ls[t] + ls[t + 32]);
        atomicAdd(&rep[32 + t], lq[t] + lq[t + 32]);
    }
}

// ---- fused: final BN + prediction dot + per-block segment readout. ----
__global__ __launch_bounds__(256) void bn_pred_readout(
    const float* __restrict__ obuf, const float* __restrict__ statsR,
    const float* __restrict__ g, const float* __restrict__ b,
    const float* __restrict__ predW, const int* __restrict__ batch,
    float* __restrict__ out)
{
    __shared__ float sv[8];
    __shared__ int sb[8];
    int t = threadIdx.x;
    int idx = blockIdx.x * 256 + t;     // node*32 + c
    int c = t & 31;
    int row = t >> 5;                   // 0..7
    int n = idx >> 5;
    float sum = 0.f, sq = 0.f;
    #pragma unroll
    for (int r = 0; r < 32; ++r) {
        sum += statsR[r * 64 + c];
        sq  += statsR[r * 64 + 32 + c];
    }
    float mu = sum * (1.f / kN);
    float var = sq * (1.f / kN) - mu * mu;
    float inv = rsqrtf(var + kEps);
    float pv = 0.f;
    if (n < kN) {
        float v = (obuf[idx] - mu) * inv * g[c] + b[c];
        pv = v * predW[c];
    }
    #pragma unroll
    for (int off = 16; off > 0; off >>= 1) pv += __shfl_down(pv, off, 32);
    if (c == 0) { sv[row] = pv; sb[row] = (n < kN) ? batch[n] : -1; }
    __syncthreads();
    if (t == 0) {
        int cur = sb[0]; float acc = sv[0];
        #pragma unroll
        for (int i = 1; i < 8; ++i) {
            if (sb[i] == cur) acc += sv[i];
            else {
                if (cur >= 0) atomicAdd(&out[cur], acc);
                cur = sb[i]; acc = sv[i];
            }
        }
        if (cur >= 0) atomicAdd(&out[cur], acc);
    }
}

} // namespace

extern "C" void kernel_launch(void* const* d_in, const int* in_sizes, int n_in,
                              void* d_out, int out_size, void* d_ws, size_t ws_size,
                              hipStream_t stream)
{
    const float* x      = (const float*)d_in[0];
    const int*   ei     = (const int*)d_in[1];
    const float* ea     = (const float*)d_in[2];
    const int*   batch  = (const int*)d_in[3];
    const float* lin_W  = (const float*)d_in[4];
    const float* lin_b  = (const float*)d_in[5];
    const float* mes_W1 = (const float*)d_in[6];
    const float* mes_b1 = (const float*)d_in[7];
    const float* mes_W2 = (const float*)d_in[8];
    const float* mes_b2 = (const float*)d_in[9];
    const float* root_W = (const float*)d_in[10];
    const float* conv_b = (const float*)d_in[11];
    const float* bn_g   = (const float*)d_in[12];
    const float* bn_b   = (const float*)d_in[13];
    const float* pred_W = (const float*)d_in[14];
    const float* pred_b = (const float*)d_in[15];
    float* out = (float*)d_out;

    // ws: stats[3*2048 f, 32KB region] | deg[N] cursor[N] | hbuf[N*32]
    //     | obuf[N*32] | Y[N*192 us] | hq[3E uint4] | Wb[3*8192 us]
    char* wsb = (char*)d_ws;
    float* stats = (float*)wsb;
    int* deg     = (int*)(wsb + 32768);
    int* cursor  = deg + kN;
    float* hbuf  = (float*)(cursor + kN);
    float* obuf  = hbuf + (size_t)kN * 32;
    unsigned short* Yus = (unsigned short*)(obuf + (size_t)kN * 32);
    unsigned* Ydw = (unsigned*)Yus;
    uint4* hq    = (uint4*)(Yus + (size_t)kN * 192);
    unsigned short* Wb = (unsigned short*)(hq + (size_t)3 * kE);

    init_h<<<kNB, 1024, 0, stream>>>(x, lin_W, lin_b, hbuf, deg, stats);
    deg_hist<<<kEB, 256, 0, stream>>>(ei, deg, mes_W2, mes_b2, root_W, Wb);
    scan_fused<<<kNB, 256, 0, stream>>>(deg, cursor);
    hid_pre<<<kEB, 256, 0, stream>>>(ea, mes_W1, mes_b1, ei, cursor, hq);

    int scatBlocks = (kE / 8) * 32 / 256;   // 3125
    for (int l = 0; l < 3; ++l) {
        y_root<<<kYB, 256, 0, stream>>>(
            hbuf, obuf, Wb + (size_t)l * 8192, conv_b + l * 32,
            stats + (l ? (l - 1) * 2048 : 0),
            bn_g + (l ? (l - 1) * 32 : 0), bn_b + (l ? (l - 1) * 32 : 0),
            l == 0 ? 1 : 0, Ydw);
        edge_scat<<<scatBlocks, 256, 0, stream>>>(
            hq + (size_t)l * kE, Ydw, obuf);
        bn_reduce<<<512, 256, 0, stream>>>(obuf, stats + l * 2048, out, pred_b,
                                           l == 2 ? 1 : 0);
    }

    bn_pred_readout<<<(kN * 32 + 255) / 256, 256, 0, stream>>>(
        obuf, stats + 2 * 2048, bn_g + 64, bn_b + 64, pred_W, batch, out);
}

// Round 11
// 272.784 us; speedup vs baseline: 1.1059x; 1.1059x over previous
//
#include <hip/hip_runtime.h>

namespace {

constexpr int kN = 50000, kE = 200000, kG = 500;
constexpr float kEps = 1e-5f;
constexpr int kNB = (kN + 255) / 256;   // 196 node chunks
constexpr int kEB = (kE + 255) / 256;   // 782 edge chunks
constexpr int kYB = (kN + 63) / 64;     // 782 y_root tiles (64 nodes, 256 thr)

typedef short v8s __attribute__((ext_vector_type(8)));
typedef float v4f __attribute__((ext_vector_type(4)));

struct U3 { unsigned a, b, c; };       // 12B gather payload -> global_load_dwordx3

__device__ __forceinline__ unsigned short bf16rn(float x) {
    unsigned u = __float_as_uint(x);
    return (unsigned short)((u + 0x7FFFu + ((u >> 16) & 1u)) >> 16);
}
__device__ __forceinline__ float bf16lo(unsigned p) { return __uint_as_float(p << 16); }
__device__ __forceinline__ float bf16hi(unsigned p) { return __uint_as_float(p & 0xFFFF0000u); }
__device__ __forceinline__ unsigned pk2(float a, float b) {
    return (unsigned)bf16rn(a) | ((unsigned)bf16rn(b) << 16);
}

// ---- degree histogram by dst + fused bf16 weight prepack. ----
__global__ __launch_bounds__(256) void deg_hist(
    const int* __restrict__ ei, int* __restrict__ deg,
    const float* __restrict__ W2all, const float* __restrict__ b2all,
    const float* __restrict__ rWall, unsigned short* __restrict__ Wb)
{
    int e = blockIdx.x * 256 + threadIdx.x;
    if (e < kE) atomicAdd(&deg[ei[kE + e]], 1);
    if (e < 3 * 8192) {
        int l = e >> 13, i = e & 8191;
        int co = i >> 5, c = i & 31, d = co >> 3, k = co & 7;
        const float* W2 = W2all + (size_t)l * 5120;
        float v = (k < 5) ? W2[k * 1024 + c * 32 + d]
                : (k == 5) ? b2all[(size_t)l * 1024 + c * 32 + d]
                : (k == 6) ? rWall[(size_t)l * 1024 + c * 32 + d] : 0.f;
        Wb[(size_t)l * 8192 + co * 32 + c] = bf16rn(v);
    }
}

// ---- h = leaky(x @ lin_W + lin_b), fp32 [n][c], MFMA (A=nodes). ----
__global__ __launch_bounds__(1024) void init_h(
    const float* __restrict__ x, const float* __restrict__ W,
    const float* __restrict__ b, float* __restrict__ hbuf,
    int* __restrict__ deg, float* __restrict__ stats)
{
    __shared__ unsigned short sx[256 * 96];
    __shared__ unsigned short sW[32 * 96];
    int t = threadIdx.x;
    {
        int z = blockIdx.x * 256 + t;
        if (t < 256 && z < kN) deg[z] = 0;
        if (blockIdx.x == 0) for (int i = t; i < 1536; i += 1024) stats[i] = 0.f;
    }
    for (int i = t; i < 256 * 96; i += 1024) sx[i] = 0;
    for (int i = t; i < 32 * 96; i += 1024) sW[i] = 0;
    __syncthreads();
    int tb = blockIdx.x * 256;
    int cnt = min(256, kN - tb);
    for (int i = t; i < cnt * 75; i += 1024) {
        int n = i / 75, f = i - n * 75;
        sx[n * 96 + f] = bf16rn(x[(size_t)tb * 75 + i]);
    }
    for (int i = t; i < 75 * 32; i += 1024) {
        int f = i >> 5, c = i & 31;
        sW[c * 96 + f] = bf16rn(W[i]);
    }
    __syncthreads();
    int l15 = t & 15, quad = (t >> 4) & 3, w = t >> 6;
    #pragma unroll
    for (int tile = 0; tile < 2; ++tile) {
        v4f acc = {0.f, 0.f, 0.f, 0.f};
        #pragma unroll
        for (int kc = 0; kc < 3; ++kc) {
            v8s a  = *(const v8s*)&sx[(w * 16 + l15) * 96 + kc * 32 + quad * 8];
            v8s bb = *(const v8s*)&sW[(tile * 16 + l15) * 96 + kc * 32 + quad * 8];
            acc = __builtin_amdgcn_mfma_f32_16x16x32_bf16(a, bb, acc, 0, 0, 0);
        }
        int c = tile * 16 + l15;
        float bc = b[c];
        #pragma unroll
        for (int r = 0; r < 4; ++r) {
            int n = tb + w * 16 + quad * 4 + r;
            if (n < kN) {
                float v = acc[r] + bc;
                hbuf[(size_t)n * 32 + c] = v > 0.f ? v : 0.01f * v;
            }
        }
    }
}

// ---- scan phase 1: per-block sums. ----
__global__ __launch_bounds__(256) void scan_part(
    const int* __restrict__ deg, int* __restrict__ blkSum)
{
    __shared__ int sc[256];
    int t = threadIdx.x;
    int idx = blockIdx.x * 256 + t;
    sc[t] = (idx < kN) ? deg[idx] : 0;
    __syncthreads();
    #pragma unroll
    for (int off = 128; off > 0; off >>= 1) {
        if (t < off) sc[t] += sc[t + off];
        __syncthreads();
    }
    if (t == 0) blkSum[blockIdx.x] = sc[0];
}

// ---- scan phase 2: fused top-scan + block-local exclusive scan. ----
__global__ __launch_bounds__(256) void scan_add(
    const int* __restrict__ deg, const int* __restrict__ blkSum,
    int* __restrict__ cursor)
{
    __shared__ int sc[256];
    __shared__ int sOff;
    int t = threadIdx.x;
    sc[t] = (t < blockIdx.x) ? blkSum[t] : 0;   // blockIdx.x <= 195 < 256
    __syncthreads();
    #pragma unroll
    for (int off = 128; off > 0; off >>= 1) {
        if (t < off) sc[t] += sc[t + off];
        __syncthreads();
    }
    if (t == 0) sOff = sc[0];
    __syncthreads();
    int idx = blockIdx.x * 256 + t;
    int v = (idx < kN) ? deg[idx] : 0;
    sc[t] = v;
    __syncthreads();
    #pragma unroll
    for (int off = 1; off < 256; off <<= 1) {
        int u = (t >= off) ? sc[t - off] : 0;
        __syncthreads();
        sc[t] += u;
        __syncthreads();
    }
    if (idx < kN) cursor[idx] = sOff + sc[t] - v;
}

// ---- hid = relu(ea@W1+b1), 3 layers, into dst-sorted CSR slots. ----
__global__ __launch_bounds__(256) void hid_pre(
    const float* __restrict__ ea, const float* __restrict__ W1,
    const float* __restrict__ b1, const int* __restrict__ ei,
    int* __restrict__ cursor, uint4* __restrict__ hq)
{
    __shared__ float sE[256 * 13];
    __shared__ float sW[195];
    int t = threadIdx.x;
    for (int i = t; i < 195; i += 256) sW[i] = (i < 180) ? W1[i] : b1[i - 180];
    int base = blockIdx.x * 256;
    int cnt = min(256, kE - base);
    for (int i = t; i < cnt * 12; i += 256) {
        int el = i / 12, f = i - el * 12;
        sE[el * 13 + f] = ea[(size_t)base * 12 + i];
    }
    __syncthreads();
    if (t >= cnt) return;
    int e = base + t;
    unsigned src = (unsigned)ei[e];
    unsigned dst = (unsigned)ei[kE + e];
    int pos = atomicAdd(&cursor[dst], 1);
    float ef[12];
    #pragma unroll
    for (int j = 0; j < 12; ++j) ef[j] = sE[t * 13 + j];
    #pragma unroll
    for (int l = 0; l < 3; ++l) {
        float h[5];
        #pragma unroll
        for (int k = 0; k < 5; ++k) h[k] = sW[180 + l * 5 + k];
        #pragma unroll
        for (int f = 0; f < 12; ++f)
            #pragma unroll
            for (int k = 0; k < 5; ++k)
                h[k] = fmaf(ef[f], sW[l * 60 + f * 5 + k], h[k]);
        #pragma unroll
        for (int k = 0; k < 5; ++k) h[k] = h[k] > 0.f ? h[k] : 0.f;
        hq[(size_t)l * kE + pos] = make_uint4(
            pk2(h[0], h[1]), pk2(h[2], h[3]),
            (unsigned)bf16rn(h[4]) | (src << 16), dst);
    }
}

// ---- y_root v3 (273.0us-verified): ZERO LDS, zero barriers. A-fragments
// direct from prepacked Wb (L1-hot); B-fragment = own node's 8 channels
// in registers (BN consts via shfl). Stores: scattered-dword [n][96]
// (gather-optimal, R7 frozen; LDS output staging refuted R6+R9). ----
__global__ __launch_bounds__(256) void y_root(
    const float* __restrict__ hbuf, float* __restrict__ obuf,
    const unsigned short* __restrict__ Wb, const float* __restrict__ convb,
    const float* __restrict__ statsR,
    const float* __restrict__ gPrev, const float* __restrict__ bPrev,
    int first, unsigned* __restrict__ Ydw)
{
    int t = threadIdx.x;
    int l15 = t & 15, quad = (t >> 4) & 3, w = t >> 6;
    int n = blockIdx.x * 64 + w * 16 + l15;
    int c0 = quad * 8;
    float muO = 0.f, ivgO = 0.f, bbO = 0.f;
    if (!first) {
        int c = t & 31;
        float sum = 0.f, sq = 0.f;
        #pragma unroll
        for (int r = 0; r < 8; ++r) {
            sum += statsR[r * 64 + c];
            sq  += statsR[r * 64 + 32 + c];
        }
        float m = sum * (1.f / kN);
        float var = sq * (1.f / kN) - m * m;
        muO = m; ivgO = rsqrtf(var + kEps) * gPrev[c]; bbO = bPrev[c];
    }
    v8s bn_ = {0, 0, 0, 0, 0, 0, 0, 0};
    if (n < kN) {
        if (first) {
            const float* hp = hbuf + (size_t)n * 32 + c0;
            #pragma unroll
            for (int j = 0; j < 8; ++j)
                bn_[j] = (short)bf16rn(hp[j]);
        } else {
            const float* op = obuf + (size_t)n * 32 + c0;
            #pragma unroll
            for (int j = 0; j < 8; ++j) {
                float m  = __shfl(muO,  c0 + j, 32);
                float iv = __shfl(ivgO, c0 + j, 32);
                float bv = __shfl(bbO,  c0 + j, 32);
                float v = (op[j] - m) * iv + bv;
                v = v > 0.f ? v : 0.01f * v;
                bn_[j] = (short)bf16rn(v);
            }
        }
    }
    #pragma unroll
    for (int i = 0; i < 16; ++i) {
        v8s a = *(const v8s*)&Wb[(i * 16 + l15) * 32 + c0];
        v4f acc = {0.f, 0.f, 0.f, 0.f};
        acc = __builtin_amdgcn_mfma_f32_16x16x32_bf16(a, bn_, acc, 0, 0, 0);
        if (n < kN) {
            int cb = i * 16 + quad * 4;
            int d = cb >> 3, koff = cb & 7;
            if (koff == 0) {
                Ydw[(size_t)n * 96 + d * 3]     = pk2(acc[0], acc[1]); // k0,k1
                Ydw[(size_t)n * 96 + d * 3 + 1] = pk2(acc[2], acc[3]); // k2,k3
            } else {
                Ydw[(size_t)n * 96 + d * 3 + 2] = pk2(acc[0], acc[1]); // k4,k5
                obuf[(size_t)n * 32 + d] = acc[2] + convb[d];          // k6
            }
        }
    }
}

// ---- edge_scat: 8 edges/group, 12B dwordx3 gathers, run-merged atomics. ----
__global__ __launch_bounds__(256) void edge_scat(
    const uint4* __restrict__ hq, const unsigned* __restrict__ Ydw,
    float* __restrict__ obuf)
{
    int gid = blockIdx.x * 256 + threadIdx.x;
    int grp = gid >> 5;                 // exactly kE/8 = 25000 groups
    int d = gid & 31;
    int e0 = grp * 8;
    uint4 q0 = hq[e0],     q1 = hq[e0 + 1], q2 = hq[e0 + 2], q3 = hq[e0 + 3];
    uint4 q4 = hq[e0 + 4], q5 = hq[e0 + 5], q6 = hq[e0 + 6], q7 = hq[e0 + 7];
    U3 P0 = *(const U3*)(Ydw + ((q0.z >> 16) * 96u + d * 3u));
    U3 P1 = *(const U3*)(Ydw + ((q1.z >> 16) * 96u + d * 3u));
    U3 P2 = *(const U3*)(Ydw + ((q2.z >> 16) * 96u + d * 3u));
    U3 P3 = *(const U3*)(Ydw + ((q3.z >> 16) * 96u + d * 3u));
    U3 P4 = *(const U3*)(Ydw + ((q4.z >> 16) * 96u + d * 3u));
    U3 P5 = *(const U3*)(Ydw + ((q5.z >> 16) * 96u + d * 3u));
    U3 P6 = *(const U3*)(Ydw + ((q6.z >> 16) * 96u + d * 3u));
    U3 P7 = *(const U3*)(Ydw + ((q7.z >> 16) * 96u + d * 3u));
    float m0 = bf16hi(P0.c);
    m0 = fmaf(bf16lo(q0.x), bf16lo(P0.a), m0);
    m0 = fmaf(bf16hi(q0.x), bf16hi(P0.a), m0);
    m0 = fmaf(bf16lo(q0.y), bf16lo(P0.b), m0);
    m0 = fmaf(bf16hi(q0.y), bf16hi(P0.b), m0);
    m0 = fmaf(bf16lo(q0.z), bf16lo(P0.c), m0);
    float m1 = bf16hi(P1.c);
    m1 = fmaf(bf16lo(q1.x), bf16lo(P1.a), m1);
    m1 = fmaf(bf16hi(q1.x), bf16hi(P1.a), m1);
    m1 = fmaf(bf16lo(q1.y), bf16lo(P1.b), m1);
    m1 = fmaf(bf16hi(q1.y), bf16hi(P1.b), m1);
    m1 = fmaf(bf16lo(q1.z), bf16lo(P1.c), m1);
    float m2 = bf16hi(P2.c);
    m2 = fmaf(bf16lo(q2.x), bf16lo(P2.a), m2);
    m2 = fmaf(bf16hi(q2.x), bf16hi(P2.a), m2);
    m2 = fmaf(bf16lo(q2.y), bf16lo(P2.b), m2);
    m2 = fmaf(bf16hi(q2.y), bf16hi(P2.b), m2);
    m2 = fmaf(bf16lo(q2.z), bf16lo(P2.c), m2);
    float m3 = bf16hi(P3.c);
    m3 = fmaf(bf16lo(q3.x), bf16lo(P3.a), m3);
    m3 = fmaf(bf16hi(q3.x), bf16hi(P3.a), m3);
    m3 = fmaf(bf16lo(q3.y), bf16lo(P3.b), m3);
    m3 = fmaf(bf16hi(q3.y), bf16hi(P3.b), m3);
    m3 = fmaf(bf16lo(q3.z), bf16lo(P3.c), m3);
    float m4 = bf16hi(P4.c);
    m4 = fmaf(bf16lo(q4.x), bf16lo(P4.a), m4);
    m4 = fmaf(bf16hi(q4.x), bf16hi(P4.a), m4);
    m4 = fmaf(bf16lo(q4.y), bf16lo(P4.b), m4);
    m4 = fmaf(bf16hi(q4.y), bf16hi(P4.b), m4);
    m4 = fmaf(bf16lo(q4.z), bf16lo(P4.c), m4);
    float m5 = bf16hi(P5.c);
    m5 = fmaf(bf16lo(q5.x), bf16lo(P5.a), m5);
    m5 = fmaf(bf16hi(q5.x), bf16hi(P5.a), m5);
    m5 = fmaf(bf16lo(q5.y), bf16lo(P5.b), m5);
    m5 = fmaf(bf16hi(q5.y), bf16hi(P5.b), m5);
    m5 = fmaf(bf16lo(q5.z), bf16lo(P5.c), m5);
    float m6 = bf16hi(P6.c);
    m6 = fmaf(bf16lo(q6.x), bf16lo(P6.a), m6);
    m6 = fmaf(bf16hi(q6.x), bf16hi(P6.a), m6);
    m6 = fmaf(bf16lo(q6.y), bf16lo(P6.b), m6);
    m6 = fmaf(bf16hi(q6.y), bf16hi(P6.b), m6);
    m6 = fmaf(bf16lo(q6.z), bf16lo(P6.c), m6);
    float m7 = bf16hi(P7.c);
    m7 = fmaf(bf16lo(q7.x), bf16lo(P7.a), m7);
    m7 = fmaf(bf16hi(q7.x), bf16hi(P7.a), m7);
    m7 = fmaf(bf16lo(q7.y), bf16lo(P7.b), m7);
    m7 = fmaf(bf16hi(q7.y), bf16hi(P7.b), m7);
    m7 = fmaf(bf16lo(q7.z), bf16lo(P7.c), m7);
    float acc = m0;
    unsigned cur = q0.w;
    if (q1.w == cur) acc += m1;
    else { atomicAdd(&obuf[cur * 32u + d], acc); cur = q1.w; acc = m1; }
    if (q2.w == cur) acc += m2;
    else { atomicAdd(&obuf[cur * 32u + d], acc); cur = q2.w; acc = m2; }
    if (q3.w == cur) acc += m3;
    else { atomicAdd(&obuf[cur * 32u + d], acc); cur = q3.w; acc = m3; }
    if (q4.w == cur) acc += m4;
    else { atomicAdd(&obuf[cur * 32u + d], acc); cur = q4.w; acc = m4; }
    if (q5.w == cur) acc += m5;
    else { atomicAdd(&obuf[cur * 32u + d], acc); cur = q5.w; acc = m5; }
    if (q6.w == cur) acc += m6;
    else { atomicAdd(&obuf[cur * 32u + d], acc); cur = q6.w; acc = m6; }
    if (q7.w == cur) acc += m7;
    else { atomicAdd(&obuf[cur * 32u + d], acc); cur = q7.w; acc = m7; }
    atomicAdd(&obuf[cur * 32u + d], acc);
}

// ---- BN stats into 8 replica buffers; last layer also inits out=pred_b. ----
__global__ __launch_bounds__(256) void bn_reduce(
    const float* __restrict__ obuf, float* __restrict__ statsR,
    float* __restrict__ out, const float* __restrict__ pred_b, int last)
{
    __shared__ float ls[256];
    __shared__ float lq[256];
    int t = threadIdx.x;
    {
        int gi = blockIdx.x * 256 + t;
        if (last && gi < kG) out[gi] = pred_b[0];
    }
    int c = t & 31, row = t >> 5;
    float s = 0.f, q = 0.f;
    for (int n = blockIdx.x * 8 + row; n < kN; n += gridDim.x * 8) {
        float v = obuf[(size_t)n * 32 + c];
        s += v; q += v * v;
    }
    ls[t] = s; lq[t] = q;
    __syncthreads();
    if (t < 128) { ls[t] += ls[t + 128]; lq[t] += lq[t + 128]; }
    __syncthreads();
    if (t < 64) { ls[t] += ls[t + 64]; lq[t] += lq[t + 64]; }
    __syncthreads();
    if (t < 32) {
        float* rep = statsR + (blockIdx.x & 7) * 64;
        atomicAdd(&rep[t], ls[t] + ls[t + 32]);
        atomicAdd(&rep[32 + t], lq[t] + lq[t + 32]);
    }
}

// ---- fused: final BN + prediction dot + per-block segment readout. ----
__global__ __launch_bounds__(256) void bn_pred_readout(
    const float* __restrict__ obuf, const float* __restrict__ statsR,
    const float* __restrict__ g, const float* __restrict__ b,
    const float* __restrict__ predW, const int* __restrict__ batch,
    float* __restrict__ out)
{
    __shared__ float sv[8];
    __shared__ int sb[8];
    int t = threadIdx.x;
    int idx = blockIdx.x * 256 + t;     // node*32 + c
    int c = t & 31;
    int row = t >> 5;                   // 0..7
    int n = idx >> 5;
    float sum = 0.f, sq = 0.f;
    #pragma unroll
    for (int r = 0; r < 8; ++r) {
        sum += statsR[r * 64 + c];
        sq  += statsR[r * 64 + 32 + c];
    }
    float mu = sum * (1.f / kN);
    float var = sq * (1.f / kN) - mu * mu;
    float inv = rsqrtf(var + kEps);
    float pv = 0.f;
    if (n < kN) {
        float v = (obuf[idx] - mu) * inv * g[c] + b[c];
        pv = v * predW[c];
    }
    #pragma unroll
    for (int off = 16; off > 0; off >>= 1) pv += __shfl_down(pv, off, 32);
    if (c == 0) { sv[row] = pv; sb[row] = (n < kN) ? batch[n] : -1; }
    __syncthreads();
    if (t == 0) {
        int cur = sb[0]; float acc = sv[0];
        #pragma unroll
        for (int i = 1; i < 8; ++i) {
            if (sb[i] == cur) acc += sv[i];
            else {
                if (cur >= 0) atomicAdd(&out[cur], acc);
                cur = sb[i]; acc = sv[i];
            }
        }
        if (cur >= 0) atomicAdd(&out[cur], acc);
    }
}

} // namespace

extern "C" void kernel_launch(void* const* d_in, const int* in_sizes, int n_in,
                              void* d_out, int out_size, void* d_ws, size_t ws_size,
                              hipStream_t stream)
{
    const float* x      = (const float*)d_in[0];
    const int*   ei     = (const int*)d_in[1];
    const float* ea     = (const float*)d_in[2];
    const int*   batch  = (const int*)d_in[3];
    const float* lin_W  = (const float*)d_in[4];
    const float* lin_b  = (const float*)d_in[5];
    const float* mes_W1 = (const float*)d_in[6];
    const float* mes_b1 = (const float*)d_in[7];
    const float* mes_W2 = (const float*)d_in[8];
    const float* mes_b2 = (const float*)d_in[9];
    const float* root_W = (const float*)d_in[10];
    const float* conv_b = (const float*)d_in[11];
    const float* bn_g   = (const float*)d_in[12];
    const float* bn_b   = (const float*)d_in[13];
    const float* pred_W = (const float*)d_in[14];
    const float* pred_b = (const float*)d_in[15];
    float* out = (float*)d_out;

    // ws: stats[1536 f, 8KB pad] | deg[N] cursor[N] blkSum[256]
    //     | hbuf[N*32 f] | obuf[N*32 f] | Y[N*192 us] | hq[3E uint4] | Wb[3*8192 us]
    char* wsb = (char*)d_ws;
    float* stats = (float*)wsb;
    int* deg     = (int*)(wsb + 8192);
    int* cursor  = deg + kN;
    int* blkSum  = cursor + kN;
    float* hbuf  = (float*)(blkSum + 256);
    float* obuf  = hbuf + (size_t)kN * 32;
    unsigned short* Yus = (unsigned short*)(obuf + (size_t)kN * 32);
    unsigned* Ydw = (unsigned*)Yus;
    uint4* hq    = (uint4*)(Yus + (size_t)kN * 192);
    unsigned short* Wb = (unsigned short*)(hq + (size_t)3 * kE);

    init_h<<<kNB, 1024, 0, stream>>>(x, lin_W, lin_b, hbuf, deg, stats);
    deg_hist<<<kEB, 256, 0, stream>>>(ei, deg, mes_W2, mes_b2, root_W, Wb);
    scan_part<<<kNB, 256, 0, stream>>>(deg, blkSum);
    scan_add<<<kNB, 256, 0, stream>>>(deg, blkSum, cursor);
    hid_pre<<<kEB, 256, 0, stream>>>(ea, mes_W1, mes_b1, ei, cursor, hq);

    int scatBlocks = (kE / 8) * 32 / 256;   // 3125
    for (int l = 0; l < 3; ++l) {
        y_root<<<kYB, 256, 0, stream>>>(
            hbuf, obuf, Wb + (size_t)l * 8192, conv_b + l * 32,
            stats + (l ? (l - 1) * 512 : 0),
            bn_g + (l ? (l - 1) * 32 : 0), bn_b + (l ? (l - 1) * 32 : 0),
            l == 0 ? 1 : 0, Ydw);
        edge_scat<<<scatBlocks, 256, 0, stream>>>(
            hq + (size_t)l * kE, Ydw, obuf);
        bn_reduce<<<512, 256, 0, stream>>>(obuf, stats + l * 512, out, pred_b,
                                           l == 2 ? 1 : 0);
    }

    bn_pred_readout<<<(kN * 32 + 255) / 256, 256, 0, stream>>>(
        obuf, stats + 2 * 512, bn_g + 64, bn_b + 64, pred_W, batch, out);
}